// Round 4
// baseline (154.794 us; speedup 1.0000x reference)
//
#include <hip/hip_runtime.h>
#include <hip/hip_bf16.h>

// Block-circulant conv == GEMM  out[b,oc,r] = sum_k A[b*1024+r, k] * B[k, oc]
//   A = flat-reshaped im2col(x), implicit via 3 dj-shifted masked bf16 x-copies.
//   B[k,oc] = w[oc>>6][k>>6][((oc&63)-(k&63))&63]  (circulant expansion)
//
// R10 DIAGNOSTIC: two theory-backed restructures (R8 im2col-elim, R9
//     quad-buffer/1-barrier) both produced ZERO total delta -> the inferred
//     "mfma ~40us" budget is falsified, and prep/mfma have never actually
//     appeared in the top-5 profile (all slots are harness re-poison fills).
//     This round measures the controllable share directly: launch prep x3 +
//     mfma x3 (idempotent, graph-safe). dur = dur_R8 + 2*(prep+mfma).
//     GEMM schedule reverted to R8's best-measured triple-buffer form.
//     Pre-committed read: ~125us -> kernels ~15us (fuse/accept-floor next);
//     ~180us -> kernels ~45us (8-phase GEMM next); ~94us -> timing model wrong.

#define QK 2304
#define NOC 512
#define QB 36
#define XPLN 1088              // 34 rows * 32 cols per (dj,b,c) plane
#define MROWS_FALLBACK 8192

typedef __attribute__((ext_vector_type(8))) short short8;
typedef __attribute__((ext_vector_type(4))) float floatx4;

__device__ __forceinline__ ushort f2bf(float f) {
    __hip_bfloat16 h = __float2bfloat16(f);
    return *reinterpret_cast<ushort*>(&h);
}

__device__ __forceinline__ void async16(const void* g, void* l) {
    __builtin_amdgcn_global_load_lds((const __attribute__((address_space(1))) void*)g,
                                     (__attribute__((address_space(3))) void*)l, 16, 0, 0);
}

// ---------------- prep v4: 3x dj-shifted masked bf16 x-copies + B expand ----
#define PREP_A_BLOCKS 2048    // 8 b * 256 c
#define PREP_B_BLOCKS 576     // 512 rows * 288 8-elem chunks / 256

__global__ __launch_bounds__(256) void bcc_prep(const float* __restrict__ x,
                                                const float* __restrict__ w,
                                                ushort* __restrict__ wsX,
                                                ushort* __restrict__ wsB) {
    if (blockIdx.x < PREP_A_BLOCKS) {
        __shared__ float img[1024];
        const int bb = blockIdx.x >> 8, c = blockIdx.x & 255;
        const float* src = x + ((size_t)bb * 256 + c) * 1024;
        *(float4*)&img[threadIdx.x * 4] = *(const float4*)&src[threadIdx.x * 4];
        __syncthreads();

        // wsX[dj][b][c][i][j] = (0<=i-1<32 && 0<=j+dj-1<32) ? x[b][c][i-1][j+dj-1] : 0
        for (int t = threadIdx.x; t < 816; t += 256) {
            const int cp = t / 272;            // dj
            const int rem = t - cp * 272;
            const int i = rem >> 3, j0 = (rem & 7) * 4;
            const int srow = i - 1;
            const bool rok = (unsigned)srow < 32u;
            ushort u[4];
            #pragma unroll
            for (int e = 0; e < 4; ++e) {
                int scol = j0 + e + cp - 1;
                float v = (rok && (unsigned)scol < 32u) ? img[srow * 32 + scol] : 0.f;
                u[e] = f2bf(v);
            }
            *(ushort4*)&wsX[((size_t)(cp * 2048 + bb * 256 + c)) * XPLN + i * 32 + j0] =
                make_ushort4(u[0], u[1], u[2], u[3]);
        }
    } else {
        int t = (blockIdx.x - PREP_A_BLOCKS) * 256 + threadIdx.x;  // 0..147455
        int n = t / 288;
        int o = t - n * 288;
        int p = n >> 6, tt = n & 63;
        int k0 = o * 8;
        ushort u[8];
        #pragma unroll
        for (int e = 0; e < 8; ++e) {
            int k = k0 + e;
            int q = k >> 6, s = k & 63;
            u[e] = f2bf(w[(p * QB + q) * 64 + ((tt - s) & 63)]);
        }
        *(ushort4*)&wsB[(size_t)n * QK + k0]     = make_ushort4(u[0], u[1], u[2], u[3]);
        *(ushort4*)&wsB[(size_t)n * QK + k0 + 4] = make_ushort4(u[4], u[5], u[6], u[7]);
    }
}

// ---------------- main GEMM: 128x128 tile, 8 waves, 64x64 wave-tiles,
// ---------------- 2-way k-interleave, TRIPLE-buffer + raw vmcnt(8) (R8) --
__global__ __launch_bounds__(512) void bcc_mfma(const ushort* __restrict__ X,
                                                const ushort* __restrict__ Bm,
                                                float* __restrict__ out) {
    __shared__ ushort smem[3][2][128 * 64];   // [buf][A/B][row*64+chunk] 96 KB

    const int tid = threadIdx.x;
    const int l = tid & 63, w = tid >> 6;      // 8 waves
    const int t3 = w & 3, ks = w >> 2;         // tile id, k-half
    const int wm = t3 & 1, wn = t3 >> 1;       // 2x2 grid of 64x64 tiles

    // XCD-affinity decode: 4 blocks sharing an A-tile -> same (lin&7) == XCD
    const int lin = blockIdx.x;                // 0..255
    const int n_idx = (lin >> 3) & 3;
    const int m_idx = ((lin >> 5) << 3) | (lin & 7);
    const int n0 = n_idx * 128;
    const int m0 = m_idx * 128;
    const int b  = m0 >> 10, r0 = m0 & 1023;
    const int bc0 = b << 8;

    const int lr = l & 15, lq = l >> 4;        // quarter-wave split
    const int lrow = l >> 3;                   // staging row in 8-group
    const int lkoff = ((l & 7) ^ (lrow & 7)) * 8;  // swizzled source chunk

    floatx4 acc[4][4];
    #pragma unroll
    for (int i = 0; i < 4; ++i)
        #pragma unroll
        for (int j = 0; j < 4; ++j) acc[i][j] = (floatx4){0.f, 0.f, 0.f, 0.f};

    auto stage = [&](int q, int buf) {
        const int kb = q * 64;
        // implicit im2col address for the t=0 staging row (t=1 is +18 planes)
        const int r  = r0 + w * 16 + lrow;
        const int fb = r * QK + kb + lkoff;            // flat A col within batch
        const int kf = fb >> 10, loc = fb & 1023;
        const int c  = (kf * 7282) >> 16;              // kf/9 (magic, kf<2304)
        const int kk = kf - c * 9;
        const int di = (kk * 11) >> 5;                 // kk/3
        const int dj = kk - di * 3;
        const size_t ei = (size_t)((dj << 11) + bc0 + c) * XPLN
                        + ((loc >> 5) + di) * 32 + (loc & 31);
        const size_t bofs = (size_t)(n0 + w * 16 + lrow) * QK + kb + lkoff;
        #pragma unroll
        for (int t = 0; t < 2; ++t) {
            const int row8 = w * 16 + t * 8;
            async16(X  + ei + t * 2176,                // +8 rows = +18 planes
                    &smem[buf][0][row8 * 64]);
            async16(Bm + bofs + (size_t)t * 8 * QK,
                    &smem[buf][1][row8 * 64]);
        }
    };

    stage(0, 0);
    stage(1, 1);
    const int ca = ks * 4 + lq;                // logical 16B chunk (k-half)
    for (int q = 0; q < QB; ++q) {
        const int buf = q % 3;
        if (q + 2 < QB) {
            stage(q + 2, (q + 2) % 3);
            asm volatile("s_waitcnt vmcnt(8)" ::: "memory");  // drain stage(q) only
        } else if (q + 1 < QB) {
            asm volatile("s_waitcnt vmcnt(4)" ::: "memory");
        } else {
            asm volatile("s_waitcnt vmcnt(0)" ::: "memory");
        }
        __builtin_amdgcn_s_barrier();
        asm volatile("" ::: "memory");

        short8 av[4], bv[4];
        #pragma unroll
        for (int i = 0; i < 4; ++i) {
            int Ra = wm * 64 + i * 16 + lr;
            av[i] = *(const short8*)&smem[buf][0][Ra * 64 + ((ca ^ (Ra & 7)) * 8)];
        }
        #pragma unroll
        for (int j = 0; j < 4; ++j) {
            int Rb = wn * 64 + j * 16 + lr;
            bv[j] = *(const short8*)&smem[buf][1][Rb * 64 + ((ca ^ (Rb & 7)) * 8)];
        }
        // operand-swapped: D rows = oc, cols = r (r-contiguous stores)
        #pragma unroll
        for (int i = 0; i < 4; ++i)
            #pragma unroll
            for (int j = 0; j < 4; ++j)
                acc[i][j] = __builtin_amdgcn_mfma_f32_16x16x32_bf16(bv[j], av[i], acc[i][j], 0, 0, 0);

        asm volatile("" ::: "memory");
        __builtin_amdgcn_s_barrier();
    }

    // ---- combine k-halves through LDS, then store ----
    __syncthreads();
    float* fsm = (float*)&smem[0][0][0];       // 64 KB of the 96 KB
    if (ks == 1) {
        #pragma unroll
        for (int i = 0; i < 4; ++i)
            #pragma unroll
            for (int j = 0; j < 4; ++j)
                *(floatx4*)&fsm[t3 * 4096 + (i * 4 + j) * 256 + l * 4] = acc[i][j];
    }
    __syncthreads();
    if (ks == 0) {
        #pragma unroll
        for (int i = 0; i < 4; ++i) {
            int rr = r0 + wm * 64 + i * 16 + lr;
            #pragma unroll
            for (int j = 0; j < 4; ++j) {
                floatx4 o4 = *(const floatx4*)&fsm[t3 * 4096 + (i * 4 + j) * 256 + l * 4];
                #pragma unroll
                for (int e = 0; e < 4; ++e) {
                    int oc = n0 + wn * 64 + j * 16 + lq * 4 + e;
                    out[((size_t)b * NOC + oc) * 1024 + rr] = acc[i][j][e] + o4[e];
                }
            }
        }
    }
}

// ---------------- round-1 fp32 fallback (ws too small) ----------------
__global__ __launch_bounds__(256) void bcc_gemm_f32(
    const float* __restrict__ x, const float* __restrict__ w,
    float* __restrict__ out) {
    __shared__ float Asf[64][68];
    __shared__ float Wsf[64][68];
    const int tid = threadIdx.x;
    const int tn = tid & 15, tm = tid >> 4;
    const int p = blockIdx.x;
    const int m0 = blockIdx.y * 64;
    const int b = m0 >> 10, r0 = m0 & 1023;
    const float* xb = x + (size_t)b * (256 * 32 * 32);
    float acc[4][4] = {};
    for (int q = 0; q < QB; ++q) {
        #pragma unroll
        for (int i = 0; i < 16; ++i) {
            int idx = i * 256 + tid;
            int s = idx & 63, mm = idx >> 6;
            int flat = (r0 + mm) * QK + q * 64 + s;
            int feat = flat >> 10, loc = flat & 1023;
            int c = feat / 9, kk = feat - c * 9;
            int hi = (loc >> 5) + (kk / 3) - 1;
            int wi = (loc & 31) + (kk % 3) - 1;
            float v = 0.0f;
            if ((unsigned)hi < 32u && (unsigned)wi < 32u)
                v = xb[(c * 32 + hi) * 32 + wi];
            Asf[mm][s] = v;
        }
        const float* wb = w + (p * QB + q) * 64;
        #pragma unroll
        for (int i = 0; i < 16; ++i) {
            int idx = i * 256 + tid;
            int t = idx & 63, s = idx >> 6;
            Wsf[s][t] = wb[(t - s) & 63];
        }
        __syncthreads();
        #pragma unroll
        for (int s0 = 0; s0 < 64; s0 += 4) {
            float4 a4[4], b4[4];
            #pragma unroll
            for (int i2 = 0; i2 < 4; ++i2)
                a4[i2] = *(const float4*)&Asf[tm * 4 + i2][s0];
            #pragma unroll
            for (int ss = 0; ss < 4; ++ss)
                b4[ss] = *(const float4*)&Wsf[s0 + ss][tn * 4];
            #pragma unroll
            for (int i2 = 0; i2 < 4; ++i2) {
                const float* av = (const float*)&a4[i2];
                #pragma unroll
                for (int ss = 0; ss < 4; ++ss) {
                    float a = av[ss];
                    acc[i2][0] += a * b4[ss].x;
                    acc[i2][1] += a * b4[ss].y;
                    acc[i2][2] += a * b4[ss].z;
                    acc[i2][3] += a * b4[ss].w;
                }
            }
        }
        __syncthreads();
    }
    float* outb = out + (size_t)b * NOC * 1024;
    const int r_base = r0 + tm * 4;
    #pragma unroll
    for (int j = 0; j < 4; ++j) {
        int oc = p * 64 + tn * 4 + j;
        float4 v = make_float4(acc[0][j], acc[1][j], acc[2][j], acc[3][j]);
        *(float4*)&outb[(size_t)oc * 1024 + r_base] = v;
    }
}

extern "C" void kernel_launch(void* const* d_in, const int* in_sizes, int n_in,
                              void* d_out, int out_size, void* d_ws, size_t ws_size,
                              hipStream_t stream) {
    const float* x = (const float*)d_in[0];
    const float* w = (const float*)d_in[1];
    float* out = (float*)d_out;

    const size_t bytesX = (size_t)3 * 2048 * XPLN * sizeof(ushort);  // 13,369,344
    const size_t bytesB = (size_t)NOC * QK * sizeof(ushort);         //  2,359,296

    if (ws_size >= bytesX + bytesB) {
        ushort* wsX = (ushort*)d_ws;
        ushort* wsB = (ushort*)((char*)d_ws + bytesX);
        // DIAGNOSTIC x3: prep and mfma are idempotent; extra launches add
        // exactly 2*(prep+mfma) to dur_us -> measures the controllable share.
        bcc_prep<<<PREP_A_BLOCKS + PREP_B_BLOCKS, 256, 0, stream>>>(x, w, wsX, wsB);
        bcc_prep<<<PREP_A_BLOCKS + PREP_B_BLOCKS, 256, 0, stream>>>(x, w, wsX, wsB);
        bcc_prep<<<PREP_A_BLOCKS + PREP_B_BLOCKS, 256, 0, stream>>>(x, w, wsX, wsB);
        bcc_mfma<<<256, 512, 0, stream>>>(wsX, wsB, out);
        bcc_mfma<<<256, 512, 0, stream>>>(wsX, wsB, out);
        bcc_mfma<<<256, 512, 0, stream>>>(wsX, wsB, out);
    } else {
        bcc_gemm_f32<<<dim3(8, MROWS_FALLBACK / 64), 256, 0, stream>>>(x, w, out);
    }
}

// Round 5
// 96.041 us; speedup vs baseline: 1.6118x; 1.6118x over previous
//
#include <hip/hip_runtime.h>
#include <hip/hip_bf16.h>

// Block-circulant conv == GEMM  out[b,oc,r] = sum_k A[b*1024+r, k] * B[k, oc]
//   A = flat-reshaped im2col(x), implicit via 3 dj-shifted masked bf16 x-copies.
//   B[k,oc] = w[oc>>6][k>>6][((oc&63)-(k&63))&63]  (circulant expansion)
//
// R11: R10 diag measured prep+mfma ~= 30.5us (fixed harness floor ~63.4us).
//     mfma ~= 22-24us => ~820 TF = the 2-barrier-structure ceiling; ~75% of
//     each K-step is vmcnt+barrier drain (1 block/CU -> nothing covers it).
//     Change: BK 64->128 (36->18 steps): HALVES barrier/vmcnt events while
//     doubling per-step compute. Same proven rhythm: barrier1 -> stage(q+1)
//     -> vmcnt(8) (q+1 stays in flight across compute) -> barrier2 -> MFMA.
//     Staging: 8-row x 64-k-half segments (1KB linear LDS per async16,
//     m104), XOR swizzle (l&7)^(l>>3) folded into per-lane GLOBAL chunk so
//     the im2col decode is h-only (2 decodes/stage). Read: 2-way bank = free.
//     LDS 2 bufs x (32KB A + 32KB B) = 128KB, still 1 block/CU.
//     Prediction: mfma -25..35% -> total ~87-90us.

#define QK 2304
#define NOC 512
#define QB 36                  // prep B-expand still indexes w by q<36
#define QB2 18                 // GEMM K-steps at BK=128
#define XPLN 1088              // 34 rows * 32 cols per (dj,b,c) plane
#define MROWS_FALLBACK 8192

typedef __attribute__((ext_vector_type(8))) short short8;
typedef __attribute__((ext_vector_type(4))) float floatx4;

__device__ __forceinline__ ushort f2bf(float f) {
    __hip_bfloat16 h = __float2bfloat16(f);
    return *reinterpret_cast<ushort*>(&h);
}

__device__ __forceinline__ void async16(const void* g, void* l) {
    __builtin_amdgcn_global_load_lds((const __attribute__((address_space(1))) void*)g,
                                     (__attribute__((address_space(3))) void*)l, 16, 0, 0);
}

// ---------------- prep v4: 3x dj-shifted masked bf16 x-copies + B expand ----
#define PREP_A_BLOCKS 2048    // 8 b * 256 c
#define PREP_B_BLOCKS 576     // 512 rows * 288 8-elem chunks / 256

__global__ __launch_bounds__(256) void bcc_prep(const float* __restrict__ x,
                                                const float* __restrict__ w,
                                                ushort* __restrict__ wsX,
                                                ushort* __restrict__ wsB) {
    if (blockIdx.x < PREP_A_BLOCKS) {
        __shared__ float img[1024];
        const int bb = blockIdx.x >> 8, c = blockIdx.x & 255;
        const float* src = x + ((size_t)bb * 256 + c) * 1024;
        *(float4*)&img[threadIdx.x * 4] = *(const float4*)&src[threadIdx.x * 4];
        __syncthreads();

        // wsX[dj][b][c][i][j] = (0<=i-1<32 && 0<=j+dj-1<32) ? x[b][c][i-1][j+dj-1] : 0
        for (int t = threadIdx.x; t < 816; t += 256) {
            const int cp = t / 272;            // dj
            const int rem = t - cp * 272;
            const int i = rem >> 3, j0 = (rem & 7) * 4;
            const int srow = i - 1;
            const bool rok = (unsigned)srow < 32u;
            ushort u[4];
            #pragma unroll
            for (int e = 0; e < 4; ++e) {
                int scol = j0 + e + cp - 1;
                float v = (rok && (unsigned)scol < 32u) ? img[srow * 32 + scol] : 0.f;
                u[e] = f2bf(v);
            }
            *(ushort4*)&wsX[((size_t)(cp * 2048 + bb * 256 + c)) * XPLN + i * 32 + j0] =
                make_ushort4(u[0], u[1], u[2], u[3]);
        }
    } else {
        int t = (blockIdx.x - PREP_A_BLOCKS) * 256 + threadIdx.x;  // 0..147455
        int n = t / 288;
        int o = t - n * 288;
        int p = n >> 6, tt = n & 63;
        int k0 = o * 8;
        ushort u[8];
        #pragma unroll
        for (int e = 0; e < 8; ++e) {
            int k = k0 + e;
            int q = k >> 6, s = k & 63;
            u[e] = f2bf(w[(p * QB + q) * 64 + ((tt - s) & 63)]);
        }
        *(ushort4*)&wsB[(size_t)n * QK + k0]     = make_ushort4(u[0], u[1], u[2], u[7 - 7]);
        // ^ keep identical semantics: element 3 is u[3]
        *(ushort4*)&wsB[(size_t)n * QK + k0]     = make_ushort4(u[0], u[1], u[2], u[3]);
        *(ushort4*)&wsB[(size_t)n * QK + k0 + 4] = make_ushort4(u[4], u[5], u[6], u[7]);
    }
}

// ---------------- main GEMM: 128x128 tile, 8 waves, 64x64 wave-tiles,
// ---------------- 2-way k-interleave, BK=128, double-buffer, 2 barriers +
// ---------------- counted vmcnt(8) per 128-k step ------------------------
__global__ __launch_bounds__(512) void bcc_mfma(const ushort* __restrict__ X,
                                                const ushort* __restrict__ Bm,
                                                float* __restrict__ out) {
    // LDS tile layout (per A/B): [g=row/8][h=khalf][row&7][slot3][8 elems]
    //   ushort off = g*1024 + h*512 + (row&7)*64 + slot3*8
    //   slot3 holds global chunk (h*8 + (slot3 ^ (row&7)))  (XOR swizzle)
    __shared__ ushort smem[2][2][16384];   // [buf][A/B] 128 KB

    const int tid = threadIdx.x;
    const int l = tid & 63, w = tid >> 6;      // 8 waves
    const int t3 = w & 3, ks = w >> 2;         // tile id, k-half (64 of 128)
    const int wm = t3 & 1, wn = t3 >> 1;       // 2x2 grid of 64x64 tiles

    // XCD-affinity decode: 4 blocks sharing an A-tile -> same (lin&7) == XCD
    const int lin = blockIdx.x;                // 0..255
    const int n_idx = (lin >> 3) & 3;
    const int m_idx = ((lin >> 5) << 3) | (lin & 7);
    const int n0 = n_idx * 128;
    const int m0 = m_idx * 128;
    const int b  = m0 >> 10, r0 = m0 & 1023;
    const int bc0 = b << 8;

    const int lr = l & 15, lq = l >> 4;        // fragment row / k-subchunk
    const int lrow = l >> 3, lch = l & 7;      // staging: row-in-8, chunk3
    const int scl = lch ^ lrow;                // swizzled source chunk (low 3)

    floatx4 acc[4][4];
    #pragma unroll
    for (int i = 0; i < 4; ++i)
        #pragma unroll
        for (int j = 0; j < 4; ++j) acc[i][j] = (floatx4){0.f, 0.f, 0.f, 0.f};

    auto stage = [&](int q, int buf) {
        const int kb = q * 128;
        // im2col decode per k-half h (row = r0 + w*16 + lrow; gg adds +8 rows
        // = +18432 flat = +2 c-planes = +2*XPLN, loc/di/dj unchanged)
        const int r = r0 + w * 16 + lrow;
        size_t eiA[2];
        #pragma unroll
        for (int h = 0; h < 2; ++h) {
            const int fb = r * QK + kb + h * 64 + scl * 8;
            const int kf = fb >> 10, loc = fb & 1023;
            const int c  = (kf * 7282) >> 16;          // kf/9 (magic, kf<2304)
            const int k9 = kf - c * 9;
            const int di = (k9 * 11) >> 5;             // k9/3
            const int dj = k9 - di * 3;
            eiA[h] = (size_t)((dj << 11) + bc0 + c) * XPLN
                   + ((loc >> 5) + di) * 32 + (loc & 31);
        }
        const size_t bB = (size_t)(n0 + w * 16 + lrow) * QK + kb + scl * 8;
        #pragma unroll
        for (int gg = 0; gg < 2; ++gg)
            #pragma unroll
            for (int h = 0; h < 2; ++h) {
                const int dst = (w * 2 + gg) * 1024 + h * 512;  // ushorts
                async16(X + eiA[h] + gg * (2 * XPLN), &smem[buf][0][dst]);
                async16(Bm + bB + (size_t)gg * (8 * QK) + h * 64, &smem[buf][1][dst]);
            }
    };

    stage(0, 0);
    for (int q = 0; q < QB2; ++q) {
        const int buf = q & 1;
        __builtin_amdgcn_s_barrier();              // all waves done reading buf^1
        asm volatile("" ::: "memory");
        if (q + 1 < QB2) {
            stage(q + 1, buf ^ 1);                 // 8 async16 into idle buffer
            asm volatile("s_waitcnt vmcnt(8)" ::: "memory");  // drain stage(q) only
        } else {
            asm volatile("s_waitcnt vmcnt(0)" ::: "memory");
        }
        __builtin_amdgcn_s_barrier();              // buf q fully staged
        asm volatile("" ::: "memory");

        #pragma unroll
        for (int kk = 0; kk < 2; ++kk) {
            const int ca = ks * 8 + kk * 4 + lq;   // chunk 0..15, h = ks
            short8 av[4], bv[4];
            #pragma unroll
            for (int i = 0; i < 4; ++i) {
                int Ra = wm * 64 + i * 16 + lr;
                av[i] = *(const short8*)&smem[buf][0][
                    (Ra >> 3) * 1024 + (ca >> 3) * 512 + (Ra & 7) * 64 + ((ca ^ Ra) & 7) * 8];
            }
            #pragma unroll
            for (int j = 0; j < 4; ++j) {
                int Rb = wn * 64 + j * 16 + lr;
                bv[j] = *(const short8*)&smem[buf][1][
                    (Rb >> 3) * 1024 + (ca >> 3) * 512 + (Rb & 7) * 64 + ((ca ^ Rb) & 7) * 8];
            }
            // operand-swapped: D rows = oc, cols = r (r-contiguous stores)
            #pragma unroll
            for (int i = 0; i < 4; ++i)
                #pragma unroll
                for (int j = 0; j < 4; ++j)
                    acc[i][j] = __builtin_amdgcn_mfma_f32_16x16x32_bf16(bv[j], av[i], acc[i][j], 0, 0, 0);
        }
        asm volatile("" ::: "memory");
    }

    // ---- combine k-halves through LDS, then store ----
    __syncthreads();
    float* fsm = (float*)&smem[0][0][0];       // 64 KB of the 128 KB
    if (ks == 1) {
        #pragma unroll
        for (int i = 0; i < 4; ++i)
            #pragma unroll
            for (int j = 0; j < 4; ++j)
                *(floatx4*)&fsm[t3 * 4096 + (i * 4 + j) * 256 + l * 4] = acc[i][j];
    }
    __syncthreads();
    if (ks == 0) {
        #pragma unroll
        for (int i = 0; i < 4; ++i) {
            int rr = r0 + wm * 64 + i * 16 + lr;
            #pragma unroll
            for (int j = 0; j < 4; ++j) {
                floatx4 o4 = *(const floatx4*)&fsm[t3 * 4096 + (i * 4 + j) * 256 + l * 4];
                #pragma unroll
                for (int e = 0; e < 4; ++e) {
                    int oc = n0 + wn * 64 + j * 16 + lq * 4 + e;
                    out[((size_t)b * NOC + oc) * 1024 + rr] = acc[i][j][e] + o4[e];
                }
            }
        }
    }
}

// ---------------- round-1 fp32 fallback (ws too small) ----------------
__global__ __launch_bounds__(256) void bcc_gemm_f32(
    const float* __restrict__ x, const float* __restrict__ w,
    float* __restrict__ out) {
    __shared__ float Asf[64][68];
    __shared__ float Wsf[64][68];
    const int tid = threadIdx.x;
    const int tn = tid & 15, tm = tid >> 4;
    const int p = blockIdx.x;
    const int m0 = blockIdx.y * 64;
    const int b = m0 >> 10, r0 = m0 & 1023;
    const float* xb = x + (size_t)b * (256 * 32 * 32);
    float acc[4][4] = {};
    for (int q = 0; q < QB; ++q) {
        #pragma unroll
        for (int i = 0; i < 16; ++i) {
            int idx = i * 256 + tid;
            int s = idx & 63, mm = idx >> 6;
            int flat = (r0 + mm) * QK + q * 64 + s;
            int feat = flat >> 10, loc = flat & 1023;
            int c = feat / 9, kk = feat - c * 9;
            int hi = (loc >> 5) + (kk / 3) - 1;
            int wi = (loc & 31) + (kk % 3) - 1;
            float v = 0.0f;
            if ((unsigned)hi < 32u && (unsigned)wi < 32u)
                v = xb[(c * 32 + hi) * 32 + wi];
            Asf[mm][s] = v;
        }
        const float* wb = w + (p * QB + q) * 64;
        #pragma unroll
        for (int i = 0; i < 16; ++i) {
            int idx = i * 256 + tid;
            int t = idx & 63, s = idx >> 6;
            Wsf[s][t] = wb[(t - s) & 63];
        }
        __syncthreads();
        #pragma unroll
        for (int s0 = 0; s0 < 64; s0 += 4) {
            float4 a4[4], b4[4];
            #pragma unroll
            for (int i2 = 0; i2 < 4; ++i2)
                a4[i2] = *(const float4*)&Asf[tm * 4 + i2][s0];
            #pragma unroll
            for (int ss = 0; ss < 4; ++ss)
                b4[ss] = *(const float4*)&Wsf[s0 + ss][tn * 4];
            #pragma unroll
            for (int i2 = 0; i2 < 4; ++i2) {
                const float* av = (const float*)&a4[i2];
                #pragma unroll
                for (int ss = 0; ss < 4; ++ss) {
                    float a = av[ss];
                    acc[i2][0] += a * b4[ss].x;
                    acc[i2][1] += a * b4[ss].y;
                    acc[i2][2] += a * b4[ss].z;
                    acc[i2][3] += a * b4[ss].w;
                }
            }
        }
        __syncthreads();
    }
    float* outb = out + (size_t)b * NOC * 1024;
    const int r_base = r0 + tm * 4;
    #pragma unroll
    for (int j = 0; j < 4; ++j) {
        int oc = p * 64 + tn * 4 + j;
        float4 v = make_float4(acc[0][j], acc[1][j], acc[2][j], acc[3][j]);
        *(float4*)&outb[(size_t)oc * 1024 + r_base] = v;
    }
}

extern "C" void kernel_launch(void* const* d_in, const int* in_sizes, int n_in,
                              void* d_out, int out_size, void* d_ws, size_t ws_size,
                              hipStream_t stream) {
    const float* x = (const float*)d_in[0];
    const float* w = (const float*)d_in[1];
    float* out = (float*)d_out;

    const size_t bytesX = (size_t)3 * 2048 * XPLN * sizeof(ushort);  // 13,369,344
    const size_t bytesB = (size_t)NOC * QK * sizeof(ushort);         //  2,359,296

    if (ws_size >= bytesX + bytesB) {
        ushort* wsX = (ushort*)d_ws;
        ushort* wsB = (ushort*)((char*)d_ws + bytesX);
        bcc_prep<<<PREP_A_BLOCKS + PREP_B_BLOCKS, 256, 0, stream>>>(x, w, wsX, wsB);
        bcc_mfma<<<256, 512, 0, stream>>>(wsX, wsB, out);
    } else {
        bcc_gemm_f32<<<dim3(8, MROWS_FALLBACK / 64), 256, 0, stream>>>(x, w, out);
    }
}